// Round 8
// baseline (204.107 us; speedup 1.0000x reference)
//
#include <hip/hip_runtime.h>
#include <hip/hip_cooperative_groups.h>
#include <math.h>

namespace cg = cooperative_groups;

#define BB 16
#define TT 1024
#define DD 512
#define T1 (TT + 1)
#define PS 1028   // padded per-batch LDS stride (floats); PS*4 % 16 == 0
#define TAIL_C 0.45f
#define CH 8      // t-rows per wave in alphas phase
#define NBLK 256
#define NTHR 256
#define NWAVES (NBLK * (NTHR / 64))   // 1024 wave slots

// 32-step chain over one chunk held in 8 float4 registers.
// fract(s) == reference's conditional subtract-1 (exact on s in [0,2)).
__device__ __forceinline__ void chain32(const float4* buf, float& integ,
                                        float4* out) {
#pragma unroll
    for (int j = 0; j < 8; ++j) {
        float4 v = buf[j];
        float4 o;
        float s;
        s = integ + v.x; o.x = s; asm("v_fract_f32 %0, %1" : "=v"(integ) : "v"(s));
        s = integ + v.y; o.y = s; asm("v_fract_f32 %0, %1" : "=v"(integ) : "v"(s));
        s = integ + v.z; o.z = s; asm("v_fract_f32 %0, %1" : "=v"(integ) : "v"(s));
        s = integ + v.w; o.w = s; asm("v_fract_f32 %0, %1" : "=v"(integ) : "v"(s));
        out[j] = o;
    }
}

__global__ __launch_bounds__(NTHR) void cif_fused(
    const float* __restrict__ hidden, const float* __restrict__ mask,
    const float* __restrict__ conv_w, const float* __restrict__ conv_b,
    const float* __restrict__ lin_w, const float* __restrict__ lin_b,
    float* __restrict__ acoustic, float* __restrict__ token_num,
    float* __restrict__ alphas2, float* __restrict__ cif_peak,
    int* __restrict__ fire_pos, int* __restrict__ n_fires)
{
    cg::grid_group grid = cg::this_grid();
    __shared__ float s_buf[BB * PS];   // 65.8 KB (block 0 only uses it)

    const int tid = threadIdx.x;
    const int lane = tid & 63;
    const int gwave = blockIdx.x * (NTHR / 64) + (tid >> 6);

    // ============================ Phase 1: alphas ============================
    for (int task = gwave; task < BB * (TT / CH); task += NWAVES) {
        const int b = task / (TT / CH);
        const int c = task % (TT / CH);
        const int t0 = c * CH;
        const int d0 = lane * 8;

        float cw[24], cb[8], lw[8];
        {
            const float4* p = (const float4*)(conv_w + (size_t)d0 * 3);
#pragma unroll
            for (int j = 0; j < 6; ++j) {
                float4 v = p[j];
                cw[j * 4 + 0] = v.x; cw[j * 4 + 1] = v.y;
                cw[j * 4 + 2] = v.z; cw[j * 4 + 3] = v.w;
            }
            float4 b0 = *(const float4*)(conv_b + d0);
            float4 b1 = *(const float4*)(conv_b + d0 + 4);
            cb[0]=b0.x; cb[1]=b0.y; cb[2]=b0.z; cb[3]=b0.w;
            cb[4]=b1.x; cb[5]=b1.y; cb[6]=b1.z; cb[7]=b1.w;
            float4 l0 = *(const float4*)(lin_w + d0);
            float4 l1 = *(const float4*)(lin_w + d0 + 4);
            lw[0]=l0.x; lw[1]=l0.y; lw[2]=l0.z; lw[3]=l0.w;
            lw[4]=l1.x; lw[5]=l1.y; lw[6]=l1.z; lw[7]=l1.w;
        }

        const float* base = hidden + (size_t)b * TT * DD + d0;

        float rows[CH + 2][8];
#pragma unroll
        for (int r = 0; r < CH + 2; ++r) {
            const int t = t0 - 1 + r;
            if (t >= 0 && t < TT) {
                float4 a  = *(const float4*)(base + (size_t)t * DD);
                float4 bq = *(const float4*)(base + (size_t)t * DD + 4);
                rows[r][0]=a.x;  rows[r][1]=a.y;  rows[r][2]=a.z;  rows[r][3]=a.w;
                rows[r][4]=bq.x; rows[r][5]=bq.y; rows[r][6]=bq.z; rows[r][7]=bq.w;
            } else {
#pragma unroll
                for (int j = 0; j < 8; ++j) rows[r][j] = 0.f;
            }
        }

        float acc[CH];
#pragma unroll
        for (int r = 0; r < CH; ++r) {
            float s = 0.f;
#pragma unroll
            for (int j = 0; j < 8; ++j) {
                float x = fmaf(cw[3*j],   rows[r][j],
                          fmaf(cw[3*j+1], rows[r+1][j],
                          fmaf(cw[3*j+2], rows[r+2][j], cb[j]))) + rows[r+1][j];
                x = fmaxf(x, 0.f);
                s = fmaf(x, lw[j], s);
            }
            acc[r] = s;
        }

#pragma unroll
        for (int r = 0; r < CH; ++r) {
#pragma unroll
            for (int off = 32; off; off >>= 1) acc[r] += __shfl_xor(acc[r], off, 64);
        }

        if (lane < CH) {
            float v = acc[0];
#pragma unroll
            for (int r = 1; r < CH; ++r) v = (lane == r) ? acc[r] : v;
            const int t = t0 + lane;
            float logit = v + lin_b[0];
            float alpha = 1.f / (1.f + expf(-logit));
            float m = mask[b * TT + t];
            float a = fmaxf(alpha, 0.f) * m;              // SMOOTH=1, NOISE=0
            float m2 = (t == 0) ? 1.0f : mask[b * TT + t - 1];
            alphas2[(size_t)b * T1 + t] = a + (m2 - m) * TAIL_C;
        } else if (lane == CH && c == 0) {
            alphas2[(size_t)b * T1 + TT] = mask[b * TT + TT - 1] * TAIL_C;
        }
    }

    grid.sync();

    // ===================== Phase 2: block 0 — CIF chain ======================
    if (blockIdx.x == 0) {
        // stage alphas -> padded LDS rows (float4 global loads)
        {
            const float4* src = (const float4*)alphas2;
            for (int i = tid; i < (BB * T1) / 4; i += NTHR) {
                float4 v = src[i];
                const int e = i * 4;
                int b = e / T1;
                int t = e - b * T1;
                float el[4] = {v.x, v.y, v.z, v.w};
#pragma unroll
                for (int j = 0; j < 4; ++j) {
                    int bb = b, tt = t + j;
                    if (tt >= T1) { bb += 1; tt -= T1; }
                    s_buf[bb * PS + tt] = el[j];
                }
            }
        }
        __syncthreads();

        // token_num = floor(sum alphas2 per batch) — identical order to r2..r7
        {
            const int b = tid >> 4, i = tid & 15;
            float part = 0.f;
            for (int t = i; t < T1; t += 16) part += s_buf[b * PS + t];
            part += __shfl_xor(part, 1, 64);
            part += __shfl_xor(part, 2, 64);
            part += __shfl_xor(part, 4, 64);
            part += __shfl_xor(part, 8, 64);
            if (i == 0) token_num[b] = floorf(part);
        }
        __syncthreads();   // all token reads done before chain overwrites s_buf

        // serial chain, in-place (alphas -> peaks), chunk-level register dbuf
        if (tid < BB) {
            float4* sb4 = (float4*)(s_buf + tid * PS);
            float4 A[8], Bv[8], OA[8], OB[8];
#pragma unroll
            for (int j = 0; j < 8; ++j) A[j] = sb4[j];       // chunk 0
            float integ = 0.f;
            for (int c = 0; c < 32; c += 2) {
#pragma unroll
                for (int j = 0; j < 8; ++j) Bv[j] = sb4[(c + 1) * 8 + j];
                chain32(A, integ, OA);
#pragma unroll
                for (int j = 0; j < 8; ++j) sb4[c * 8 + j] = OA[j];
                if (c + 2 < 32) {
#pragma unroll
                    for (int j = 0; j < 8; ++j) A[j] = sb4[(c + 2) * 8 + j];
                }
                chain32(Bv, integ, OB);
#pragma unroll
                for (int j = 0; j < 8; ++j) sb4[(c + 1) * 8 + j] = OB[j];
            }
            float s = integ + s_buf[tid * PS + TT];          // tail t = 1024
            s_buf[tid * PS + TT] = s;
        }
        __syncthreads();

        // cooperative writeback of peaks (padded LDS -> flat global, float4)
        {
            float4* dst = (float4*)cif_peak;
            for (int i = tid; i < (BB * T1) / 4; i += NTHR) {
                const int e = i * 4;
                int b = e / T1;
                int t = e - b * T1;
                float4 v;
                float* pv = &v.x;
#pragma unroll
                for (int j = 0; j < 4; ++j) {
                    int bb = b, tt = t + j;
                    if (tt >= T1) { bb += 1; tt -= T1; }
                    pv[j] = s_buf[bb * PS + tt];
                }
                dst[i] = v;
            }
        }

        // fire compaction: wave w handles batches 4w..4w+3; ballot + rank.
        {
            const int wv = tid >> 6;
            for (int bi = 0; bi < 4; ++bi) {
                const int b = wv * 4 + bi;
                const float* sp = s_buf + b * PS;
                int k0 = 0;
                for (int base = 0; base < T1; base += 64) {
                    const int t = base + lane;
                    const float p = (t < T1) ? sp[t] : 0.f;
                    const bool fire = (p >= 1.0f);
                    unsigned long long mb = __ballot(fire);
                    if (fire) {
                        int rank = __popcll(mb & ((1ull << lane) - 1));
                        fire_pos[b * T1 + k0 + rank] = t;
                    }
                    k0 += __popcll(mb);
                }
                if (lane == 0) n_fires[b] = k0;
            }
        }
    }

    grid.sync();

    // ============================ Phase 3: gather ============================
    for (int task = gwave; task < BB * T1; task += NWAVES) {
        const int b = task / T1;
        const int k = task % T1;
        const int d0 = lane * 8;

        float4 acc0 = make_float4(0.f, 0.f, 0.f, 0.f);
        float4 acc1 = make_float4(0.f, 0.f, 0.f, 0.f);

        const int nf = n_fires[b];
        if (k < nf) {
            const int te = fire_pos[b * T1 + k];
            int ts; float wstart;
            if (k == 0) {
                ts = 0;
                wstart = alphas2[b * T1];                // alpha_0
            } else {
                ts = fire_pos[b * T1 + k - 1];
                wstart = cif_peak[b * T1 + ts] - 1.0f;   // rem at prev fire
            }
            const float ae = alphas2[b * T1 + te];
            const float wend = 1.0f - cif_peak[b * T1 + te] + ae;  // dist at te

            for (int t = ts; t <= te; ++t) {
                if (t >= TT) break;   // hidden2 row TT is zeros
                float w = (t == te) ? wend : (t == ts) ? wstart
                                           : alphas2[b * T1 + t];
                const float* hrow = hidden + (size_t)(b * TT + t) * DD + d0;
                float4 h0 = *(const float4*)hrow;
                float4 h1 = *(const float4*)(hrow + 4);
                acc0.x = fmaf(w, h0.x, acc0.x);
                acc0.y = fmaf(w, h0.y, acc0.y);
                acc0.z = fmaf(w, h0.z, acc0.z);
                acc0.w = fmaf(w, h0.w, acc0.w);
                acc1.x = fmaf(w, h1.x, acc1.x);
                acc1.y = fmaf(w, h1.y, acc1.y);
                acc1.z = fmaf(w, h1.z, acc1.z);
                acc1.w = fmaf(w, h1.w, acc1.w);
            }
        }
        float* arow = acoustic + (size_t)(b * T1 + k) * DD + d0;
        *(float4*)arow = acc0;
        *(float4*)(arow + 4) = acc1;
    }
}

extern "C" void kernel_launch(void* const* d_in, const int* in_sizes, int n_in,
                              void* d_out, int out_size, void* d_ws, size_t ws_size,
                              hipStream_t stream) {
    const float* hidden = (const float*)d_in[0];
    const float* mask   = (const float*)d_in[1];
    const float* conv_w = (const float*)d_in[2];
    const float* conv_b = (const float*)d_in[3];
    const float* lin_w  = (const float*)d_in[4];
    const float* lin_b  = (const float*)d_in[5];

    float* out       = (float*)d_out;
    float* out_aco   = out;                                   // B*T1*D
    float* out_tok   = out + (size_t)BB * T1 * DD;            // B
    float* out_alp   = out_tok + BB;                          // B*T1
    float* out_peak  = out_alp + (size_t)BB * T1;             // B*T1

    int* fire_pos = (int*)d_ws;                               // B*T1 ints
    int* nf       = fire_pos + (size_t)BB * T1;               // B ints

    void* args[] = {
        (void*)&hidden, (void*)&mask, (void*)&conv_w, (void*)&conv_b,
        (void*)&lin_w, (void*)&lin_b,
        (void*)&out_aco, (void*)&out_tok, (void*)&out_alp, (void*)&out_peak,
        (void*)&fire_pos, (void*)&nf
    };
    hipLaunchCooperativeKernel((const void*)cif_fused, dim3(NBLK), dim3(NTHR),
                               args, 0, stream);
}

// Round 9
// 128.046 us; speedup vs baseline: 1.5940x; 1.5940x over previous
//
#include <hip/hip_runtime.h>
#include <math.h>

#define BB 16
#define TT 1024
#define DD 512
#define T1 (TT + 1)
#define PS 1028   // padded per-batch LDS stride (floats); PS*4 % 16 == 0
#define TAIL_C 0.45f
#define CH 8      // t-rows per wave in alphas kernel

// ws layout (ints): [0] done-flag, [1..3] pad/dummy-sink, [4 .. 4+BB*T1) fire_pos,
//                   [4+BB*T1 .. 4+BB*T1+BB) n_fires
#define WS_FLAG 0
#define WS_SINK 1
#define WS_FP   4

// ---------------------------------------------------------------------------
// Kernel 1: alphas2[b][t], t in [0,TT), plus tail element at t=TT.
// (unchanged from r7)
// ---------------------------------------------------------------------------
__global__ __launch_bounds__(256) void alphas_kernel(
    const float* __restrict__ hidden, const float* __restrict__ mask,
    const float* __restrict__ conv_w, const float* __restrict__ conv_b,
    const float* __restrict__ lin_w, const float* __restrict__ lin_b,
    float* __restrict__ alphas2)
{
    const int wave = blockIdx.x * 4 + (threadIdx.x >> 6);
    const int lane = threadIdx.x & 63;
    const int b = wave / (TT / CH);
    const int c = wave % (TT / CH);
    const int t0 = c * CH;
    const int d0 = lane * 8;

    float cw[24], cb[8], lw[8];
    {
        const float4* p = (const float4*)(conv_w + (size_t)d0 * 3);
#pragma unroll
        for (int j = 0; j < 6; ++j) {
            float4 v = p[j];
            cw[j * 4 + 0] = v.x; cw[j * 4 + 1] = v.y;
            cw[j * 4 + 2] = v.z; cw[j * 4 + 3] = v.w;
        }
        float4 b0 = *(const float4*)(conv_b + d0);
        float4 b1 = *(const float4*)(conv_b + d0 + 4);
        cb[0]=b0.x; cb[1]=b0.y; cb[2]=b0.z; cb[3]=b0.w;
        cb[4]=b1.x; cb[5]=b1.y; cb[6]=b1.z; cb[7]=b1.w;
        float4 l0 = *(const float4*)(lin_w + d0);
        float4 l1 = *(const float4*)(lin_w + d0 + 4);
        lw[0]=l0.x; lw[1]=l0.y; lw[2]=l0.z; lw[3]=l0.w;
        lw[4]=l1.x; lw[5]=l1.y; lw[6]=l1.z; lw[7]=l1.w;
    }

    const float* base = hidden + (size_t)b * TT * DD + d0;

    float rows[CH + 2][8];
#pragma unroll
    for (int r = 0; r < CH + 2; ++r) {
        const int t = t0 - 1 + r;
        if (t >= 0 && t < TT) {
            float4 a  = *(const float4*)(base + (size_t)t * DD);
            float4 bq = *(const float4*)(base + (size_t)t * DD + 4);
            rows[r][0]=a.x;  rows[r][1]=a.y;  rows[r][2]=a.z;  rows[r][3]=a.w;
            rows[r][4]=bq.x; rows[r][5]=bq.y; rows[r][6]=bq.z; rows[r][7]=bq.w;
        } else {
#pragma unroll
            for (int j = 0; j < 8; ++j) rows[r][j] = 0.f;
        }
    }

    float acc[CH];
#pragma unroll
    for (int r = 0; r < CH; ++r) {
        float s = 0.f;
#pragma unroll
        for (int j = 0; j < 8; ++j) {
            float x = fmaf(cw[3*j],   rows[r][j],
                      fmaf(cw[3*j+1], rows[r+1][j],
                      fmaf(cw[3*j+2], rows[r+2][j], cb[j]))) + rows[r+1][j];
            x = fmaxf(x, 0.f);
            s = fmaf(x, lw[j], s);
        }
        acc[r] = s;
    }

#pragma unroll
    for (int r = 0; r < CH; ++r) {
#pragma unroll
        for (int off = 32; off; off >>= 1) acc[r] += __shfl_xor(acc[r], off, 64);
    }

    if (lane < CH) {
        float v = acc[0];
#pragma unroll
        for (int r = 1; r < CH; ++r) v = (lane == r) ? acc[r] : v;
        const int t = t0 + lane;
        float logit = v + lin_b[0];
        float alpha = 1.f / (1.f + expf(-logit));
        float m = mask[b * TT + t];
        float a = fmaxf(alpha, 0.f) * m;              // SMOOTH=1, NOISE=0
        float m2 = (t == 0) ? 1.0f : mask[b * TT + t - 1];
        alphas2[(size_t)b * T1 + t] = a + (m2 - m) * TAIL_C;
    } else if (lane == CH && c == 0) {
        alphas2[(size_t)b * T1 + TT] = mask[b * TT + TT - 1] * TAIL_C;
    }
}

// 32-step chain over one chunk held in 8 float4 registers.
// fract(s) == reference's conditional subtract-1 (exact on s in [0,2)).
__device__ __forceinline__ void chain32(const float4* buf, float& integ,
                                        float4* out) {
#pragma unroll
    for (int j = 0; j < 8; ++j) {
        float4 v = buf[j];
        float4 o;
        float s;
        s = integ + v.x; o.x = s; asm("v_fract_f32 %0, %1" : "=v"(integ) : "v"(s));
        s = integ + v.y; o.y = s; asm("v_fract_f32 %0, %1" : "=v"(integ) : "v"(s));
        s = integ + v.z; o.z = s; asm("v_fract_f32 %0, %1" : "=v"(integ) : "v"(s));
        s = integ + v.w; o.w = s; asm("v_fract_f32 %0, %1" : "=v"(integ) : "v"(s));
        out[j] = o;
    }
}

// ---------------------------------------------------------------------------
// Kernel 2: block 0 = r7's phase_a verbatim (stage/token/chain/writeback/
// compaction) + done-flag store. Blocks 1..256 = ballast: stream `hidden`
// (warms L2/L3 for gather) until the flag is visible, capped at 24 passes.
// Purpose: keep the shader clock domain busy during the 1-wave serial chain
// (tests the clock-droop theory for the invariant 43 us).
// All 257 blocks co-resident: 65.8 KB LDS -> 2 blocks/CU -> capacity 512.
// ---------------------------------------------------------------------------
__global__ __launch_bounds__(256) void cif_chain(
    const float* __restrict__ alphas2, const float* __restrict__ hidden,
    float* __restrict__ token_num, float* __restrict__ cif_peak,
    int* __restrict__ ws)
{
    __shared__ float s_buf[BB * PS];   // 65.8 KB
    const int tid = threadIdx.x;

    if (blockIdx.x != 0) {
        // ---- ballast: stream hidden, poll flag (agent scope), capped ----
        const int bid = blockIdx.x - 1;                       // 0..255
        const size_t slice = (size_t)BB * TT * DD / 4 / 256;  // 8192 float4
        const float4* p = (const float4*)hidden + (size_t)bid * slice;
        float s = 0.f;
        for (int pass = 0; pass < 24; ++pass) {
            if (__hip_atomic_load(&ws[WS_FLAG], __ATOMIC_RELAXED,
                                  __HIP_MEMORY_SCOPE_AGENT) == 1) break;
            for (int i = tid; i < (int)slice; i += 256) {
                float4 v = p[i];
                s += v.x + v.y + v.z + v.w;
            }
        }
        if (s == 1.2345678e38f) ((float*)ws)[WS_SINK] = s;  // never; keeps loads
        return;
    }

    int* fire_pos = ws + WS_FP;
    int* n_fires  = ws + WS_FP + BB * T1;

    // stage alphas -> padded LDS rows (float4 global loads)
    {
        const float4* src = (const float4*)alphas2;
        for (int i = tid; i < (BB * T1) / 4; i += 256) {
            float4 v = src[i];
            const int e = i * 4;
            int b = e / T1;
            int t = e - b * T1;
            float el[4] = {v.x, v.y, v.z, v.w};
#pragma unroll
            for (int j = 0; j < 4; ++j) {
                int bb = b, tt = t + j;
                if (tt >= T1) { bb += 1; tt -= T1; }
                s_buf[bb * PS + tt] = el[j];
            }
        }
    }
    __syncthreads();

    // token_num = floor(sum alphas2 per batch) — identical order to r2..r7
    {
        const int b = tid >> 4, i = tid & 15;
        float part = 0.f;
        for (int t = i; t < T1; t += 16) part += s_buf[b * PS + t];
        part += __shfl_xor(part, 1, 64);
        part += __shfl_xor(part, 2, 64);
        part += __shfl_xor(part, 4, 64);
        part += __shfl_xor(part, 8, 64);
        if (i == 0) token_num[b] = floorf(part);
    }
    __syncthreads();   // token reads done before chain overwrites s_buf

    // serial chain, in-place (alphas -> peaks), chunk-level register dbuf
    if (tid < BB) {
        float4* sb4 = (float4*)(s_buf + tid * PS);
        float4 A[8], Bv[8], OA[8], OB[8];
#pragma unroll
        for (int j = 0; j < 8; ++j) A[j] = sb4[j];       // chunk 0
        float integ = 0.f;
        for (int c = 0; c < 32; c += 2) {
#pragma unroll
            for (int j = 0; j < 8; ++j) Bv[j] = sb4[(c + 1) * 8 + j];
            chain32(A, integ, OA);
#pragma unroll
            for (int j = 0; j < 8; ++j) sb4[c * 8 + j] = OA[j];
            if (c + 2 < 32) {
#pragma unroll
                for (int j = 0; j < 8; ++j) A[j] = sb4[(c + 2) * 8 + j];
            }
            chain32(Bv, integ, OB);
#pragma unroll
            for (int j = 0; j < 8; ++j) sb4[(c + 1) * 8 + j] = OB[j];
        }
        float s = integ + s_buf[tid * PS + TT];          // tail t = 1024
        s_buf[tid * PS + TT] = s;
    }
    __syncthreads();

    // cooperative writeback of peaks (padded LDS -> flat global, float4)
    {
        float4* dst = (float4*)cif_peak;
        for (int i = tid; i < (BB * T1) / 4; i += 256) {
            const int e = i * 4;
            int b = e / T1;
            int t = e - b * T1;
            float4 v;
            float* pv = &v.x;
#pragma unroll
            for (int j = 0; j < 4; ++j) {
                int bb = b, tt = t + j;
                if (tt >= T1) { bb += 1; tt -= T1; }
                pv[j] = s_buf[bb * PS + tt];
            }
            dst[i] = v;
        }
    }

    // fire compaction: wave w handles batches 4w..4w+3; ballot + rank.
    {
        const int wv = tid >> 6, lane = tid & 63;
        for (int bi = 0; bi < 4; ++bi) {
            const int b = wv * 4 + bi;
            const float* sp = s_buf + b * PS;
            int k0 = 0;
            for (int base = 0; base < T1; base += 64) {
                const int t = base + lane;
                const float p = (t < T1) ? sp[t] : 0.f;
                const bool fire = (p >= 1.0f);
                unsigned long long mb = __ballot(fire);
                if (fire) {
                    int rank = __popcll(mb & ((1ull << lane) - 1));
                    fire_pos[b * T1 + k0 + rank] = t;
                }
                k0 += __popcll(mb);
            }
            if (lane == 0) n_fires[b] = k0;
        }
    }
    __syncthreads();
    if (tid == 0)
        __hip_atomic_store(&ws[WS_FLAG], 1, __ATOMIC_RELEASE,
                           __HIP_MEMORY_SCOPE_AGENT);
}

// ---------------------------------------------------------------------------
// Kernel 3: gather — one wave per acoustic output row (full TLP restored).
// (unchanged from r7, modulo ws pointers)
// ---------------------------------------------------------------------------
__global__ __launch_bounds__(256) void cif_gather(
    const float* __restrict__ hidden, const float* __restrict__ alphas2,
    const float* __restrict__ cif_peak, const int* __restrict__ ws,
    float* __restrict__ acoustic)
{
    const int* fire_pos = ws + WS_FP;
    const int* n_fires  = ws + WS_FP + BB * T1;

    const int wave = blockIdx.x * 4 + (threadIdx.x >> 6);
    const int lane = threadIdx.x & 63;
    const int b = wave / T1;
    const int k = wave % T1;
    const int d0 = lane * 8;

    float4 acc0 = make_float4(0.f, 0.f, 0.f, 0.f);
    float4 acc1 = make_float4(0.f, 0.f, 0.f, 0.f);

    const int nf = n_fires[b];
    if (k < nf) {
        const int te = fire_pos[b * T1 + k];
        int ts; float wstart;
        if (k == 0) {
            ts = 0;
            wstart = alphas2[b * T1];                // alpha_0
        } else {
            ts = fire_pos[b * T1 + k - 1];
            wstart = cif_peak[b * T1 + ts] - 1.0f;   // rem at prev fire
        }
        const float ae = alphas2[b * T1 + te];
        const float wend = 1.0f - cif_peak[b * T1 + te] + ae;  // dist at te

        for (int t = ts; t <= te; ++t) {
            if (t >= TT) break;   // hidden2 row TT is zeros
            float w = (t == te) ? wend : (t == ts) ? wstart
                                       : alphas2[b * T1 + t];
            const float* hrow = hidden + (size_t)(b * TT + t) * DD + d0;
            float4 h0 = *(const float4*)hrow;
            float4 h1 = *(const float4*)(hrow + 4);
            acc0.x = fmaf(w, h0.x, acc0.x);
            acc0.y = fmaf(w, h0.y, acc0.y);
            acc0.z = fmaf(w, h0.z, acc0.z);
            acc0.w = fmaf(w, h0.w, acc0.w);
            acc1.x = fmaf(w, h1.x, acc1.x);
            acc1.y = fmaf(w, h1.y, acc1.y);
            acc1.z = fmaf(w, h1.z, acc1.z);
            acc1.w = fmaf(w, h1.w, acc1.w);
        }
    }
    float* arow = acoustic + (size_t)(b * T1 + k) * DD + d0;
    *(float4*)arow = acc0;
    *(float4*)(arow + 4) = acc1;
}

extern "C" void kernel_launch(void* const* d_in, const int* in_sizes, int n_in,
                              void* d_out, int out_size, void* d_ws, size_t ws_size,
                              hipStream_t stream) {
    const float* hidden = (const float*)d_in[0];
    const float* mask   = (const float*)d_in[1];
    const float* conv_w = (const float*)d_in[2];
    const float* conv_b = (const float*)d_in[3];
    const float* lin_w  = (const float*)d_in[4];
    const float* lin_b  = (const float*)d_in[5];

    float* out       = (float*)d_out;
    float* out_aco   = out;                                   // B*T1*D
    float* out_tok   = out + (size_t)BB * T1 * DD;            // B
    float* out_alp   = out_tok + BB;                          // B*T1
    float* out_peak  = out_alp + (size_t)BB * T1;             // B*T1

    int* wsI = (int*)d_ws;

    alphas_kernel<<<(BB * (TT / CH)) / 4, 256, 0, stream>>>(
        hidden, mask, conv_w, conv_b, lin_w, lin_b, out_alp);

    cif_chain<<<257, 256, 0, stream>>>(
        out_alp, hidden, out_tok, out_peak, wsI);

    cif_gather<<<(BB * T1) / 4, 256, 0, stream>>>(
        hidden, out_alp, out_peak, wsI, out_aco);
}

// Round 12
// 121.495 us; speedup vs baseline: 1.6800x; 1.0539x over previous
//
#include <hip/hip_runtime.h>
#include <math.h>

#define BB 16
#define TT 1024
#define DD 512
#define T1 (TT + 1)
#define TAIL_C 0.45f
#define CH 8      // t-rows per wave in alphas kernel

// ws layout (ints): [4 .. 4+BB*T1) fire_pos, then BB n_fires
#define WS_FP 4

// ---------------------------------------------------------------------------
// Kernel 1: alphas2[b][t], t in [0,TT), plus tail element at t=TT.
// (unchanged from r7)
// ---------------------------------------------------------------------------
__global__ __launch_bounds__(256) void alphas_kernel(
    const float* __restrict__ hidden, const float* __restrict__ mask,
    const float* __restrict__ conv_w, const float* __restrict__ conv_b,
    const float* __restrict__ lin_w, const float* __restrict__ lin_b,
    float* __restrict__ alphas2)
{
    const int wave = blockIdx.x * 4 + (threadIdx.x >> 6);
    const int lane = threadIdx.x & 63;
    const int b = wave / (TT / CH);
    const int c = wave % (TT / CH);
    const int t0 = c * CH;
    const int d0 = lane * 8;

    float cw[24], cb[8], lw[8];
    {
        const float4* p = (const float4*)(conv_w + (size_t)d0 * 3);
#pragma unroll
        for (int j = 0; j < 6; ++j) {
            float4 v = p[j];
            cw[j * 4 + 0] = v.x; cw[j * 4 + 1] = v.y;
            cw[j * 4 + 2] = v.z; cw[j * 4 + 3] = v.w;
        }
        float4 b0 = *(const float4*)(conv_b + d0);
        float4 b1 = *(const float4*)(conv_b + d0 + 4);
        cb[0]=b0.x; cb[1]=b0.y; cb[2]=b0.z; cb[3]=b0.w;
        cb[4]=b1.x; cb[5]=b1.y; cb[6]=b1.z; cb[7]=b1.w;
        float4 l0 = *(const float4*)(lin_w + d0);
        float4 l1 = *(const float4*)(lin_w + d0 + 4);
        lw[0]=l0.x; lw[1]=l0.y; lw[2]=l0.z; lw[3]=l0.w;
        lw[4]=l1.x; lw[5]=l1.y; lw[6]=l1.z; lw[7]=l1.w;
    }

    const float* base = hidden + (size_t)b * TT * DD + d0;

    float rows[CH + 2][8];
#pragma unroll
    for (int r = 0; r < CH + 2; ++r) {
        const int t = t0 - 1 + r;
        if (t >= 0 && t < TT) {
            float4 a  = *(const float4*)(base + (size_t)t * DD);
            float4 bq = *(const float4*)(base + (size_t)t * DD + 4);
            rows[r][0]=a.x;  rows[r][1]=a.y;  rows[r][2]=a.z;  rows[r][3]=a.w;
            rows[r][4]=bq.x; rows[r][5]=bq.y; rows[r][6]=bq.z; rows[r][7]=bq.w;
        } else {
#pragma unroll
            for (int j = 0; j < 8; ++j) rows[r][j] = 0.f;
        }
    }

    float acc[CH];
#pragma unroll
    for (int r = 0; r < CH; ++r) {
        float s = 0.f;
#pragma unroll
        for (int j = 0; j < 8; ++j) {
            float x = fmaf(cw[3*j],   rows[r][j],
                      fmaf(cw[3*j+1], rows[r+1][j],
                      fmaf(cw[3*j+2], rows[r+2][j], cb[j]))) + rows[r+1][j];
            x = fmaxf(x, 0.f);
            s = fmaf(x, lw[j], s);
        }
        acc[r] = s;
    }

#pragma unroll
    for (int r = 0; r < CH; ++r) {
#pragma unroll
        for (int off = 32; off; off >>= 1) acc[r] += __shfl_xor(acc[r], off, 64);
    }

    if (lane < CH) {
        float v = acc[0];
#pragma unroll
        for (int r = 1; r < CH; ++r) v = (lane == r) ? acc[r] : v;
        const int t = t0 + lane;
        float logit = v + lin_b[0];
        float alpha = 1.f / (1.f + expf(-logit));
        float m = mask[b * TT + t];
        float a = fmaxf(alpha, 0.f) * m;              // SMOOTH=1, NOISE=0
        float m2 = (t == 0) ? 1.0f : mask[b * TT + t - 1];
        alphas2[(size_t)b * T1 + t] = a + (m2 - m) * TAIL_C;
    } else if (lane == CH && c == 0) {
        alphas2[(size_t)b * T1 + TT] = mask[b * TT + TT - 1] * TAIL_C;
    }
}

// ---------------------------------------------------------------------------
// Kernel 2: CIF chain, v3. 16 blocks x 64 threads; block b owns batch b.
// NO LDS, no ds ops. Alphas read at wave-uniform addresses (compiler emits
// batched s_load -> one lgkm wait per 32-step chunk, L2-hot from the token
// pass). Chain per step = v_add (SGPR operand) + v_fract; peak captured
// off-chain via predicated cndmask (pk = (lane&31)==j ? s : pk); peaks
// stored coalesced (vmcnt domain - never stalls the chain); fires compacted
// inline via ballot/popc. fract(s) == reference's conditional subtract-1
// (exact on s in [0,2), Sterbenz).
// ---------------------------------------------------------------------------
__global__ __launch_bounds__(64) void cif_chain(
    const float* __restrict__ alphas2, float* __restrict__ token_num,
    float* __restrict__ cif_peak, int* __restrict__ ws)
{
    const int b = blockIdx.x;
    const int lane = threadIdx.x;           // 0..63
    int* fire_pos = ws + WS_FP;
    int* n_fires  = ws + WS_FP + BB * T1;
    const float* A = alphas2 + b * T1;

    // token_num = floor(sum alphas) — coalesced vector loads, shfl reduce.
    // (order differs from reference pairwise sum; output-1 threshold is 9.04,
    //  a razor-edge floor flip is +-1 -> safe)
    {
        float part = 0.f;
        for (int i = lane; i < T1; i += 64) part += A[i];
#pragma unroll
        for (int off = 32; off; off >>= 1) part += __shfl_xor(part, off, 64);
        if (lane == 0) token_num[b] = floorf(part);
    }

    float integ = 0.f;
    int k0 = 0;
    for (int c = 0; c < 32; ++c) {
        const int base = c * 32;
        float pk = 0.f;
#pragma unroll
        for (int j = 0; j < 32; ++j) {
            const float a = A[base + j];        // uniform addr -> s_load
            const float s = integ + a;
            pk = ((lane & 31) == j) ? s : pk;   // off-chain capture
            asm("v_fract_f32 %0, %1" : "=v"(integ) : "v"(s));
        }
        const unsigned m32 =
            (unsigned)(__ballot(pk >= 1.0f) & 0xFFFFFFFFull);
        if (lane < 32) {
            cif_peak[b * T1 + base + lane] = pk;          // coalesced, vmcnt
            if (pk >= 1.0f) {
                const int rank = __popc(m32 & ((1u << lane) - 1));
                fire_pos[b * T1 + k0 + rank] = base + lane;
            }
        }
        k0 += __popc(m32);
    }
    // tail t = 1024
    const float s = integ + A[TT];
    if (lane == 0) {
        cif_peak[b * T1 + TT] = s;
        if (s >= 1.0f) { fire_pos[b * T1 + k0] = TT; ++k0; }
        n_fires[b] = k0;
    }
}

// ---------------------------------------------------------------------------
// Kernel 3: gather — one wave per acoustic output row. (unchanged)
// ---------------------------------------------------------------------------
__global__ __launch_bounds__(256) void cif_gather(
    const float* __restrict__ hidden, const float* __restrict__ alphas2,
    const float* __restrict__ cif_peak, const int* __restrict__ ws,
    float* __restrict__ acoustic)
{
    const int* fire_pos = ws + WS_FP;
    const int* n_fires  = ws + WS_FP + BB * T1;

    const int wave = blockIdx.x * 4 + (threadIdx.x >> 6);
    const int lane = threadIdx.x & 63;
    const int b = wave / T1;
    const int k = wave % T1;
    const int d0 = lane * 8;

    float4 acc0 = make_float4(0.f, 0.f, 0.f, 0.f);
    float4 acc1 = make_float4(0.f, 0.f, 0.f, 0.f);

    const int nf = n_fires[b];
    if (k < nf) {
        const int te = fire_pos[b * T1 + k];
        int ts; float wstart;
        if (k == 0) {
            ts = 0;
            wstart = alphas2[b * T1];                // alpha_0
        } else {
            ts = fire_pos[b * T1 + k - 1];
            wstart = cif_peak[b * T1 + ts] - 1.0f;   // rem at prev fire
        }
        const float ae = alphas2[b * T1 + te];
        const float wend = 1.0f - cif_peak[b * T1 + te] + ae;  // dist at te

        for (int t = ts; t <= te; ++t) {
            if (t >= TT) break;   // hidden2 row TT is zeros
            float w = (t == te) ? wend : (t == ts) ? wstart
                                       : alphas2[b * T1 + t];
            const float* hrow = hidden + (size_t)(b * TT + t) * DD + d0;
            float4 h0 = *(const float4*)hrow;
            float4 h1 = *(const float4*)(hrow + 4);
            acc0.x = fmaf(w, h0.x, acc0.x);
            acc0.y = fmaf(w, h0.y, acc0.y);
            acc0.z = fmaf(w, h0.z, acc0.z);
            acc0.w = fmaf(w, h0.w, acc0.w);
            acc1.x = fmaf(w, h1.x, acc1.x);
            acc1.y = fmaf(w, h1.y, acc1.y);
            acc1.z = fmaf(w, h1.z, acc1.z);
            acc1.w = fmaf(w, h1.w, acc1.w);
        }
    }
    float* arow = acoustic + (size_t)(b * T1 + k) * DD + d0;
    *(float4*)arow = acc0;
    *(float4*)(arow + 4) = acc1;
}

extern "C" void kernel_launch(void* const* d_in, const int* in_sizes, int n_in,
                              void* d_out, int out_size, void* d_ws, size_t ws_size,
                              hipStream_t stream) {
    const float* hidden = (const float*)d_in[0];
    const float* mask   = (const float*)d_in[1];
    const float* conv_w = (const float*)d_in[2];
    const float* conv_b = (const float*)d_in[3];
    const float* lin_w  = (const float*)d_in[4];
    const float* lin_b  = (const float*)d_in[5];

    float* out       = (float*)d_out;
    float* out_aco   = out;                                   // B*T1*D
    float* out_tok   = out + (size_t)BB * T1 * DD;            // B
    float* out_alp   = out_tok + BB;                          // B*T1
    float* out_peak  = out_alp + (size_t)BB * T1;             // B*T1

    int* wsI = (int*)d_ws;

    alphas_kernel<<<(BB * (TT / CH)) / 4, 256, 0, stream>>>(
        hidden, mask, conv_w, conv_b, lin_w, lin_b, out_alp);

    cif_chain<<<BB, 64, 0, stream>>>(
        out_alp, out_tok, out_peak, wsI);

    cif_gather<<<(BB * T1) / 4, 256, 0, stream>>>(
        hidden, out_alp, out_peak, wsI, out_aco);
}